// Round 10
// baseline (82.827 us; speedup 1.0000x reference)
//
#include <hip/hip_runtime.h>
#include <hip/hip_bf16.h>

#define D_IN  1024
#define D_H   512
#define L2E2  2.885390081777927f   // 2*log2(e)
#define ECLAMP 15.0f               // exp2-arg clamp: e in [2^-15, 2^15]

typedef _Float16 half8 __attribute__((ext_vector_type(8)));
typedef _Float16 half4v __attribute__((ext_vector_type(4)));
typedef float f32x4 __attribute__((ext_vector_type(4)));

// ---------------------------------------------------------------------------
// cvt: V (1024x1024 f32) -> Vh f16 ; [Wh;Wm] (1024x1024 f32) -> Wf f16
// ---------------------------------------------------------------------------
__global__ __launch_bounds__(256) void cvt_kernel(
    const float* __restrict__ V,
    const float* __restrict__ Wh, const float* __restrict__ Wm,
    _Float16* __restrict__ Vh, _Float16* __restrict__ Wf)
{
  const int idx = blockIdx.x * 256 + threadIdx.x;   // 0..262143 float4s
  {
    float4 x = ((const float4*)V)[idx];
    half4v o = { (_Float16)x.x, (_Float16)x.y, (_Float16)x.z, (_Float16)x.w };
    ((half4v*)Vh)[idx] = o;
  }
  {
    const float4* p = (idx < 131072) ? ((const float4*)Wh + idx)
                                     : ((const float4*)Wm + (idx - 131072));
    float4 x = *p;
    half4v o = { (_Float16)x.x, (_Float16)x.y, (_Float16)x.z, (_Float16)x.w };
    ((half4v*)Wf)[idx] = o;
  }
}

// ---------------------------------------------------------------------------
// proj via MFMA, k-quadrant split (R8 structure, unchanged): 32x32 tile,
// 4 waves each own K/4, LDS reduce, bias+exp2 epilogue. Grid 1024.
// ---------------------------------------------------------------------------
__global__ __launch_bounds__(256, 4) void proj_mfma_kernel(
    const _Float16* __restrict__ Vh, const _Float16* __restrict__ Wf,
    const float* __restrict__ bh, const float* __restrict__ bm,
    float* __restrict__ C)
{
  __shared__ float red[4][32][34];

  const int tid  = threadIdx.x;
  const int lane = tid & 63;
  const int wid  = tid >> 6;          // k-quarter 0..3
  const int bid  = blockIdx.x;
  const int swz  = (bid & 7) * 128 + (bid >> 3);
  const int i0   = (swz & 31) * 32;
  const int j0   = (swz >> 5) * 32;
  const int r16  = lane & 15;
  const int kg   = lane >> 4;         // k-group 0..3
  const int kb   = wid * 256;

  const _Float16* A0 = Vh + (size_t)(i0 + r16) * 1024 + kb + kg*8;
  const _Float16* A1 = A0 + 16 * 1024;
  const _Float16* B0 = Wf + (size_t)(j0 + r16) * 1024 + kb + kg*8;
  const _Float16* B1 = B0 + 16 * 1024;

  f32x4 acc00 = {0.f,0.f,0.f,0.f}, acc01 = acc00, acc10 = acc00, acc11 = acc00;
  #pragma unroll 4
  for (int k0 = 0; k0 < 256; k0 += 32) {
    half8 a0 = *(const half8*)(A0 + k0);
    half8 a1 = *(const half8*)(A1 + k0);
    half8 b0 = *(const half8*)(B0 + k0);
    half8 b1 = *(const half8*)(B1 + k0);
    acc00 = __builtin_amdgcn_mfma_f32_16x16x32_f16(a0, b0, acc00, 0, 0, 0);
    acc01 = __builtin_amdgcn_mfma_f32_16x16x32_f16(a0, b1, acc01, 0, 0, 0);
    acc10 = __builtin_amdgcn_mfma_f32_16x16x32_f16(a1, b0, acc10, 0, 0, 0);
    acc11 = __builtin_amdgcn_mfma_f32_16x16x32_f16(a1, b1, acc11, 0, 0, 0);
  }

  // C/D layout (m89-verified): col = lane&15, row = (lane>>4)*4 + reg
  #pragma unroll
  for (int fi = 0; fi < 2; ++fi) {
    #pragma unroll
    for (int fj = 0; fj < 2; ++fj) {
      const f32x4 acc = (fi == 0) ? (fj == 0 ? acc00 : acc01)
                                  : (fj == 0 ? acc10 : acc11);
      #pragma unroll
      for (int rr = 0; rr < 4; ++rr)
        red[wid][16*fi + 4*kg + rr][16*fj + r16] = acc[rr];
    }
  }
  __syncthreads();

  const int row = tid >> 3;
  const int c4  = (tid & 7) * 4;
  const float* biasp = (j0 < D_H) ? (bh + j0) : (bm + (j0 - D_H));
  float4 bias = *(const float4*)(biasp + c4);
  float4 o;
  #pragma unroll
  for (int q = 0; q < 4; ++q) {
    float s = red[0][row][c4+q] + red[1][row][c4+q]
            + red[2][row][c4+q] + red[3][row][c4+q];
    float x = (s + (&bias.x)[q]) * L2E2;
    x = fminf(fmaxf(x, -ECLAMP), ECLAMP);
    (&o.x)[q] = __builtin_amdgcn_exp2f(x);
  }
  *(float4*)(C + (size_t)(i0 + row) * 1024 + j0 + c4) = o;
}

// ---------------------------------------------------------------------------
// proj fallback (fp32 vector GEMM) when ws is too small for f16 staging.
// ---------------------------------------------------------------------------
__global__ __launch_bounds__(256) void proj_kernel(
    const float* __restrict__ V,
    const float* __restrict__ Wh, const float* __restrict__ bh,
    const float* __restrict__ Wm, const float* __restrict__ bm,
    float* __restrict__ C)
{
  __shared__ float As[16][68];
  __shared__ float Bs[16][68];

  const int tid = threadIdx.x;
  const int i0  = (blockIdx.x & 15) * 64, j0 = (blockIdx.x >> 4) * 64;
  const int ti  = tid >> 4, tj = tid & 15;
  const int sr  = tid >> 2;
  const int sk  = (tid & 3) << 2;

  const float* Wbase = (j0 < D_H) ? (Wh + (size_t)j0 * D_IN)
                                  : (Wm + (size_t)(j0 - D_H) * D_IN);
  const float* biasp = (j0 < D_H) ? (bh + j0) : (bm + (j0 - D_H));

  const float* arow = V     + (size_t)(i0 + sr) * D_IN + sk;
  const float* brow = Wbase + (size_t)sr        * D_IN + sk;

  float acc[4][4] = {};
  for (int k0 = 0; k0 < D_IN; k0 += 16) {
    float4 av = *(const float4*)(arow + k0);
    float4 bv = *(const float4*)(brow + k0);
    As[sk+0][sr] = av.x; As[sk+1][sr] = av.y; As[sk+2][sr] = av.z; As[sk+3][sr] = av.w;
    Bs[sk+0][sr] = bv.x; Bs[sk+1][sr] = bv.y; Bs[sk+2][sr] = bv.z; Bs[sk+3][sr] = bv.w;
    __syncthreads();
    #pragma unroll
    for (int kk = 0; kk < 16; ++kk) {
      float4 a = *(const float4*)&As[kk][4*ti];
      float4 b = *(const float4*)&Bs[kk][4*tj];
      #pragma unroll
      for (int x = 0; x < 4; ++x)
        #pragma unroll
        for (int y = 0; y < 4; ++y)
          acc[x][y] = fmaf((&a.x)[x], (&b.x)[y], acc[x][y]);
    }
    __syncthreads();
  }

  const int jl = 4 * tj;
  #pragma unroll
  for (int aa = 0; aa < 4; ++aa) {
    const int i = i0 + 4*ti + aa;
    float4 o;
    #pragma unroll
    for (int bb = 0; bb < 4; ++bb) {
      float x = (acc[aa][bb] + biasp[jl+bb]) * L2E2;
      x = fminf(fmaxf(x, -ECLAMP), ECLAMP);
      (&o.x)[bb] = __builtin_amdgcn_exp2f(x);
    }
    *(float4*)(C + (size_t)i * 1024 + j0 + jl) = o;
  }
}

// ---------------------------------------------------------------------------
// score: out[i][j] = b2 + sum(w2) - 2 * sum_k w2[k]/(1 + Eh[i,k]*Em[j,k])
// 64x64 tile (grid 256, 1 block/CU), 4x4 strided outputs per thread
// (i = ti+16a, j = tj+16c): delivered LDS bytes drop 3 -> 2 B/(pair*k);
// 8 ds_read_b128 per 4-k group feed 16 outputs. Stride-36 rows, zero-conflict
// maps (R9-verified pattern). 4-way k-fold, reg ping-pong pipeline, dbuf.
// XCD swizzle: each XCD's C working set ~2.25 MB -> L2-resident.
// ---------------------------------------------------------------------------
__global__ __launch_bounds__(256) void score_kernel(
    const float* __restrict__ C,
    const float* __restrict__ w2,
    const float* __restrict__ b2,
    float* __restrict__ out)
{
  __shared__ float hs[2][64][36];
  __shared__ float ms[2][64][36];
  __shared__ float wred[4];

  const int tid = threadIdx.x;
  const int bid = blockIdx.x;
  const int swz = (bid & 7) * 32 + (bid >> 3);   // grid 256 = 8 XCD * 32
  const int i0  = (swz & 15) * 64;
  const int j0  = (swz >> 4) * 64;
  const int ti  = tid >> 4, tj = tid & 15;   // outputs: i0+ti+16a, j0+tj+16c

  const int sr  = tid >> 3;                  // staging row 0..31 (R9 zero-conflict map)
  const int sk  = (tid & 7) << 2;            // staging k 0..28

  // block-reduce sum(w2)
  float sw = 0.f;
  for (int t = tid; t < D_H; t += 256) sw += w2[t];
  #pragma unroll
  for (int off = 32; off > 0; off >>= 1) sw += __shfl_down(sw, off, 64);
  if ((tid & 63) == 0) wred[tid >> 6] = sw;

  const float* hrow0 = C + (size_t)(i0 + sr)      * 1024 + sk;        // Eh rows 0..31
  const float* hrow1 = C + (size_t)(i0 + sr + 32) * 1024 + sk;        // Eh rows 32..63
  const float* mrow0 = C + (size_t)(j0 + sr)      * 1024 + D_H + sk;  // Em rows 0..31
  const float* mrow1 = C + (size_t)(j0 + sr + 32) * 1024 + D_H + sk;  // Em rows 32..63

  // prefetch chunk 0
  float4 hv0 = *(const float4*)(hrow0);
  float4 hv1 = *(const float4*)(hrow1);
  float4 mv0 = *(const float4*)(mrow0);
  float4 mv1 = *(const float4*)(mrow1);

  float acc[4][4] = {};
  int p = 0;

  // register ping-pong buffers for the group pipeline
  float4 ehA[4], emA[4], ehB[4], emB[4];

  #define LOADG(EH, EM, KK)                                            \
  {                                                                    \
    _Pragma("unroll")                                                  \
    for (int a = 0; a < 4; ++a)                                        \
      (EH)[a] = *(const float4*)&hs[p][ti + 16*a][(KK)];               \
    _Pragma("unroll")                                                  \
    for (int c = 0; c < 4; ++c)                                        \
      (EM)[c] = *(const float4*)&ms[p][tj + 16*c][(KK)];               \
  }

  #define COMPG(EH, EM, KB)                                            \
  {                                                                    \
    const float wA = w2[(KB) + 0];                                     \
    const float wB = w2[(KB) + 1];                                     \
    const float wC = w2[(KB) + 2];                                     \
    const float wD = w2[(KB) + 3];                                     \
    _Pragma("unroll")                                                  \
    for (int a = 0; a < 4; ++a) {                                      \
      _Pragma("unroll")                                                \
      for (int c = 0; c < 4; ++c) {                                    \
        float uA = fmaf((EH)[a].x, (EM)[c].x, 1.f);                    \
        float uB = fmaf((EH)[a].y, (EM)[c].y, 1.f);                    \
        float uC = fmaf((EH)[a].z, (EM)[c].z, 1.f);                    \
        float uD = fmaf((EH)[a].w, (EM)[c].w, 1.f);                    \
        float dAB = uA * uB, dCD = uC * uD;                            \
        float nAB = fmaf(wB, uA, wA * uB);                             \
        float nCD = fmaf(wD, uC, wC * uD);                             \
        float den = dAB * dCD;                                         \
        float num = fmaf(nCD, dAB, nAB * dCD);                         \
        acc[a][c] = fmaf(num, __builtin_amdgcn_rcpf(den), acc[a][c]);  \
      }                                                                \
    }                                                                  \
  }

  for (int k0 = 0; k0 < D_H; k0 += 32) {
    // stage current chunk: 4 b128 writes (16B-aligned at stride 36)
    *(float4*)&hs[p][sr][sk]      = hv0;
    *(float4*)&hs[p][sr + 32][sk] = hv1;
    *(float4*)&ms[p][sr][sk]      = mv0;
    *(float4*)&ms[p][sr + 32][sk] = mv1;
    __syncthreads();          // also covers wred on first iteration

    // issue next chunk's global loads (overlap with compute)
    if (k0 + 32 < D_H) {
      hv0 = *(const float4*)(hrow0 + k0 + 32);
      hv1 = *(const float4*)(hrow1 + k0 + 32);
      mv0 = *(const float4*)(mrow0 + k0 + 32);
      mv1 = *(const float4*)(mrow1 + k0 + 32);
    }

    // software-pipelined 8 groups: load g+1 before computing g
    LOADG(ehA, emA, 0)
    #pragma unroll
    for (int gp = 0; gp < 4; ++gp) {
      const int kk = 8 * gp;
      LOADG(ehB, emB, kk + 4)
      COMPG(ehA, emA, k0 + kk)
      if (gp < 3) { LOADG(ehA, emA, kk + 8) }
      COMPG(ehB, emB, k0 + kk + 4)
    }
    p ^= 1;
  }
  #undef LOADG
  #undef COMPG

  const float base = b2[0] + wred[0] + wred[1] + wred[2] + wred[3];
  #pragma unroll
  for (int a = 0; a < 4; ++a) {
    const int i = i0 + ti + 16*a;
    #pragma unroll
    for (int c = 0; c < 4; ++c) {
      const int j = j0 + tj + 16*c;
      out[(size_t)i * 1024 + j] = fmaf(-2.f, acc[a][c], base);
    }
  }
}

extern "C" void kernel_launch(void* const* d_in, const int* in_sizes, int n_in,
                              void* d_out, int out_size, void* d_ws, size_t ws_size,
                              hipStream_t stream) {
  const float* V  = (const float*)d_in[0];
  const float* Wh = (const float*)d_in[1];
  const float* bh = (const float*)d_in[2];
  const float* Wm = (const float*)d_in[3];
  const float* bm = (const float*)d_in[4];
  const float* w2 = (const float*)d_in[5];
  const float* b2 = (const float*)d_in[6];
  float* outp = (float*)d_out;

  char* ws = (char*)d_ws;
  float* C = (float*)ws;                                 // 4 MB: Eh|Em

  if (ws_size >= (size_t)(8u << 20)) {
    _Float16* Vh = (_Float16*)(ws + (4u << 20));         // 2 MB
    _Float16* Wf = (_Float16*)(ws + (6u << 20));         // 2 MB
    cvt_kernel<<<dim3(1024), dim3(256), 0, stream>>>(V, Wh, Wm, Vh, Wf);
    proj_mfma_kernel<<<dim3(1024), dim3(256), 0, stream>>>(Vh, Wf, bh, bm, C);
  } else {
    proj_kernel<<<dim3(256), dim3(256), 0, stream>>>(V, Wh, bh, Wm, bm, C);
  }
  score_kernel<<<dim3(256), dim3(256), 0, stream>>>(C, w2, b2, outp);
}

// Round 11
// 76.807 us; speedup vs baseline: 1.0784x; 1.0784x over previous
//
#include <hip/hip_runtime.h>
#include <hip/hip_bf16.h>

#define D_IN  1024
#define D_H   512
#define L2E2  2.885390081777927f   // 2*log2(e)
#define ECLAMP 15.0f               // exp2-arg clamp: e in [2^-15, 2^15]

typedef _Float16 half8 __attribute__((ext_vector_type(8)));
typedef _Float16 half4v __attribute__((ext_vector_type(4)));
typedef float f32x4 __attribute__((ext_vector_type(4)));

// ---------------------------------------------------------------------------
// cvt: V (1024x1024 f32) -> Vh f16 ; [Wh;Wm] (1024x1024 f32) -> Wf f16
// ---------------------------------------------------------------------------
__global__ __launch_bounds__(256) void cvt_kernel(
    const float* __restrict__ V,
    const float* __restrict__ Wh, const float* __restrict__ Wm,
    _Float16* __restrict__ Vh, _Float16* __restrict__ Wf)
{
  const int idx = blockIdx.x * 256 + threadIdx.x;   // 0..262143 float4s
  {
    float4 x = ((const float4*)V)[idx];
    half4v o = { (_Float16)x.x, (_Float16)x.y, (_Float16)x.z, (_Float16)x.w };
    ((half4v*)Vh)[idx] = o;
  }
  {
    const float4* p = (idx < 131072) ? ((const float4*)Wh + idx)
                                     : ((const float4*)Wm + (idx - 131072));
    float4 x = *p;
    half4v o = { (_Float16)x.x, (_Float16)x.y, (_Float16)x.z, (_Float16)x.w };
    ((half4v*)Wf)[idx] = o;
  }
}

// ---------------------------------------------------------------------------
// proj via MFMA, k-quadrant split (R8 structure): 32x32 tile, 4 waves each
// own K/4, LDS reduce, bias+exp2 epilogue. Grid 1024.
// ---------------------------------------------------------------------------
__global__ __launch_bounds__(256, 4) void proj_mfma_kernel(
    const _Float16* __restrict__ Vh, const _Float16* __restrict__ Wf,
    const float* __restrict__ bh, const float* __restrict__ bm,
    float* __restrict__ C)
{
  __shared__ float red[4][32][34];

  const int tid  = threadIdx.x;
  const int lane = tid & 63;
  const int wid  = tid >> 6;          // k-quarter 0..3
  const int bid  = blockIdx.x;
  const int swz  = (bid & 7) * 128 + (bid >> 3);
  const int i0   = (swz & 31) * 32;
  const int j0   = (swz >> 5) * 32;
  const int r16  = lane & 15;
  const int kg   = lane >> 4;         // k-group 0..3
  const int kb   = wid * 256;

  const _Float16* A0 = Vh + (size_t)(i0 + r16) * 1024 + kb + kg*8;
  const _Float16* A1 = A0 + 16 * 1024;
  const _Float16* B0 = Wf + (size_t)(j0 + r16) * 1024 + kb + kg*8;
  const _Float16* B1 = B0 + 16 * 1024;

  f32x4 acc00 = {0.f,0.f,0.f,0.f}, acc01 = acc00, acc10 = acc00, acc11 = acc00;
  #pragma unroll 4
  for (int k0 = 0; k0 < 256; k0 += 32) {
    half8 a0 = *(const half8*)(A0 + k0);
    half8 a1 = *(const half8*)(A1 + k0);
    half8 b0 = *(const half8*)(B0 + k0);
    half8 b1 = *(const half8*)(B1 + k0);
    acc00 = __builtin_amdgcn_mfma_f32_16x16x32_f16(a0, b0, acc00, 0, 0, 0);
    acc01 = __builtin_amdgcn_mfma_f32_16x16x32_f16(a0, b1, acc01, 0, 0, 0);
    acc10 = __builtin_amdgcn_mfma_f32_16x16x32_f16(a1, b0, acc10, 0, 0, 0);
    acc11 = __builtin_amdgcn_mfma_f32_16x16x32_f16(a1, b1, acc11, 0, 0, 0);
  }

  // C/D layout (m89-verified): col = lane&15, row = (lane>>4)*4 + reg
  #pragma unroll
  for (int fi = 0; fi < 2; ++fi) {
    #pragma unroll
    for (int fj = 0; fj < 2; ++fj) {
      const f32x4 acc = (fi == 0) ? (fj == 0 ? acc00 : acc01)
                                  : (fj == 0 ? acc10 : acc11);
      #pragma unroll
      for (int rr = 0; rr < 4; ++rr)
        red[wid][16*fi + 4*kg + rr][16*fj + r16] = acc[rr];
    }
  }
  __syncthreads();

  const int row = tid >> 3;
  const int c4  = (tid & 7) * 4;
  const float* biasp = (j0 < D_H) ? (bh + j0) : (bm + (j0 - D_H));
  float4 bias = *(const float4*)(biasp + c4);
  float4 o;
  #pragma unroll
  for (int q = 0; q < 4; ++q) {
    float s = red[0][row][c4+q] + red[1][row][c4+q]
            + red[2][row][c4+q] + red[3][row][c4+q];
    float x = (s + (&bias.x)[q]) * L2E2;
    x = fminf(fmaxf(x, -ECLAMP), ECLAMP);
    (&o.x)[q] = __builtin_amdgcn_exp2f(x);
  }
  *(float4*)(C + (size_t)(i0 + row) * 1024 + j0 + c4) = o;
}

// ---------------------------------------------------------------------------
// proj fallback (fp32 vector GEMM) when ws is too small for f16 staging.
// ---------------------------------------------------------------------------
__global__ __launch_bounds__(256) void proj_kernel(
    const float* __restrict__ V,
    const float* __restrict__ Wh, const float* __restrict__ bh,
    const float* __restrict__ Wm, const float* __restrict__ bm,
    float* __restrict__ C)
{
  __shared__ float As[16][68];
  __shared__ float Bs[16][68];

  const int tid = threadIdx.x;
  const int i0  = (blockIdx.x & 15) * 64, j0 = (blockIdx.x >> 4) * 64;
  const int ti  = tid >> 4, tj = tid & 15;
  const int sr  = tid >> 2;
  const int sk  = (tid & 3) << 2;

  const float* Wbase = (j0 < D_H) ? (Wh + (size_t)j0 * D_IN)
                                  : (Wm + (size_t)(j0 - D_H) * D_IN);
  const float* biasp = (j0 < D_H) ? (bh + j0) : (bm + (j0 - D_H));

  const float* arow = V     + (size_t)(i0 + sr) * D_IN + sk;
  const float* brow = Wbase + (size_t)sr        * D_IN + sk;

  float acc[4][4] = {};
  for (int k0 = 0; k0 < D_IN; k0 += 16) {
    float4 av = *(const float4*)(arow + k0);
    float4 bv = *(const float4*)(brow + k0);
    As[sk+0][sr] = av.x; As[sk+1][sr] = av.y; As[sk+2][sr] = av.z; As[sk+3][sr] = av.w;
    Bs[sk+0][sr] = bv.x; Bs[sk+1][sr] = bv.y; Bs[sk+2][sr] = bv.z; Bs[sk+3][sr] = bv.w;
    __syncthreads();
    #pragma unroll
    for (int kk = 0; kk < 16; ++kk) {
      float4 a = *(const float4*)&As[kk][4*ti];
      float4 b = *(const float4*)&Bs[kk][4*tj];
      #pragma unroll
      for (int x = 0; x < 4; ++x)
        #pragma unroll
        for (int y = 0; y < 4; ++y)
          acc[x][y] = fmaf((&a.x)[x], (&b.x)[y], acc[x][y]);
    }
    __syncthreads();
  }

  const int jl = 4 * tj;
  #pragma unroll
  for (int aa = 0; aa < 4; ++aa) {
    const int i = i0 + 4*ti + aa;
    float4 o;
    #pragma unroll
    for (int bb = 0; bb < 4; ++bb) {
      float x = (acc[aa][bb] + biasp[jl+bb]) * L2E2;
      x = fminf(fmaxf(x, -ECLAMP), ECLAMP);
      (&o.x)[bb] = __builtin_amdgcn_exp2f(x);
    }
    *(float4*)(C + (size_t)i * 1024 + j0 + jl) = o;
  }
}

// ---------------------------------------------------------------------------
// score_split: 64x64 tile, 4x4/thread (0.5 LDS reads/output), K split in
// halves across 2 blocks per tile -> grid 512 = 2 blocks/CU (the occupancy
// R10 lacked). kh=0 block writes base-2*sum0 to P0; kh=1 writes -2*sum1 to
// P1; combine adds. XCD swizzle keeps a tile's two halves on one XCD.
// ---------------------------------------------------------------------------
__global__ __launch_bounds__(256) void score_split_kernel(
    const float* __restrict__ C,
    const float* __restrict__ w2,
    const float* __restrict__ b2,
    float* __restrict__ P0, float* __restrict__ P1)
{
  __shared__ float hs[2][64][36];
  __shared__ float ms[2][64][36];
  __shared__ float wred[4];

  const int tid  = threadIdx.x;
  const int b    = blockIdx.x;
  const int v    = (b & 7) * 64 + (b >> 3);  // XCD-grouped virtual id
  const int tile = v >> 1;
  const int kh   = v & 1;
  const int i0   = (tile & 15) * 64;
  const int j0   = (tile >> 4) * 64;
  const int kb   = kh * 256;
  const int ti   = tid >> 4, tj = tid & 15;  // outputs: i0+ti+16a, j0+tj+16c

  const int sr   = tid >> 3;                 // staging row 0..31
  const int sk   = (tid & 7) << 2;           // staging k 0..28

  if (kh == 0) {            // block-uniform branch
    float sw = 0.f;
    for (int t = tid; t < D_H; t += 256) sw += w2[t];
    #pragma unroll
    for (int off = 32; off > 0; off >>= 1) sw += __shfl_down(sw, off, 64);
    if ((tid & 63) == 0) wred[tid >> 6] = sw;
  }

  const float* hrow0 = C + (size_t)(i0 + sr)      * 1024 + kb + sk;
  const float* hrow1 = C + (size_t)(i0 + sr + 32) * 1024 + kb + sk;
  const float* mrow0 = C + (size_t)(j0 + sr)      * 1024 + D_H + kb + sk;
  const float* mrow1 = C + (size_t)(j0 + sr + 32) * 1024 + D_H + kb + sk;

  float4 hv0 = *(const float4*)(hrow0);
  float4 hv1 = *(const float4*)(hrow1);
  float4 mv0 = *(const float4*)(mrow0);
  float4 mv1 = *(const float4*)(mrow1);

  float acc[4][4] = {};
  int p = 0;

  float4 ehA[4], emA[4], ehB[4], emB[4];

  #define LOADG(EH, EM, KK)                                            \
  {                                                                    \
    _Pragma("unroll")                                                  \
    for (int a = 0; a < 4; ++a)                                        \
      (EH)[a] = *(const float4*)&hs[p][ti + 16*a][(KK)];               \
    _Pragma("unroll")                                                  \
    for (int c = 0; c < 4; ++c)                                        \
      (EM)[c] = *(const float4*)&ms[p][tj + 16*c][(KK)];               \
  }

  #define COMPG(EH, EM, KB)                                            \
  {                                                                    \
    const float wA = w2[(KB) + 0];                                     \
    const float wB = w2[(KB) + 1];                                     \
    const float wC = w2[(KB) + 2];                                     \
    const float wD = w2[(KB) + 3];                                     \
    _Pragma("unroll")                                                  \
    for (int a = 0; a < 4; ++a) {                                      \
      _Pragma("unroll")                                                \
      for (int c = 0; c < 4; ++c) {                                    \
        float uA = fmaf((EH)[a].x, (EM)[c].x, 1.f);                    \
        float uB = fmaf((EH)[a].y, (EM)[c].y, 1.f);                    \
        float uC = fmaf((EH)[a].z, (EM)[c].z, 1.f);                    \
        float uD = fmaf((EH)[a].w, (EM)[c].w, 1.f);                    \
        float dAB = uA * uB, dCD = uC * uD;                            \
        float nAB = fmaf(wB, uA, wA * uB);                             \
        float nCD = fmaf(wD, uC, wC * uD);                             \
        float den = dAB * dCD;                                         \
        float num = fmaf(nCD, dAB, nAB * dCD);                         \
        acc[a][c] = fmaf(num, __builtin_amdgcn_rcpf(den), acc[a][c]);  \
      }                                                                \
    }                                                                  \
  }

  for (int k0 = 0; k0 < 256; k0 += 32) {
    *(float4*)&hs[p][sr][sk]      = hv0;
    *(float4*)&hs[p][sr + 32][sk] = hv1;
    *(float4*)&ms[p][sr][sk]      = mv0;
    *(float4*)&ms[p][sr + 32][sk] = mv1;
    __syncthreads();          // also covers wred on first iteration

    if (k0 + 32 < 256) {
      hv0 = *(const float4*)(hrow0 + k0 + 32);
      hv1 = *(const float4*)(hrow1 + k0 + 32);
      mv0 = *(const float4*)(mrow0 + k0 + 32);
      mv1 = *(const float4*)(mrow1 + k0 + 32);
    }

    LOADG(ehA, emA, 0)
    #pragma unroll
    for (int gp = 0; gp < 4; ++gp) {
      const int kk = 8 * gp;
      LOADG(ehB, emB, kk + 4)
      COMPG(ehA, emA, kb + k0 + kk)
      if (gp < 3) { LOADG(ehA, emA, kk + 8) }
      COMPG(ehB, emB, kb + k0 + kk + 4)
    }
    p ^= 1;
  }
  #undef LOADG
  #undef COMPG

  float base = 0.f;
  if (kh == 0) base = b2[0] + wred[0] + wred[1] + wred[2] + wred[3];
  float* Pz = kh ? P1 : P0;
  #pragma unroll
  for (int a = 0; a < 4; ++a) {
    const int i = i0 + ti + 16*a;
    #pragma unroll
    for (int c = 0; c < 4; ++c) {
      const int j = j0 + tj + 16*c;
      Pz[(size_t)i * 1024 + j] = fmaf(-2.f, acc[a][c], base);
    }
  }
}

// combine: out = P0 + P1 (full-rate float4 stream)
__global__ __launch_bounds__(256) void combine_kernel(
    const float* __restrict__ P0, const float* __restrict__ P1,
    float* __restrict__ out)
{
  const int idx = blockIdx.x * 256 + threadIdx.x;
  float4 a = ((const float4*)P0)[idx];
  float4 b = ((const float4*)P1)[idx];
  float4 o = {a.x + b.x, a.y + b.y, a.z + b.z, a.w + b.w};
  ((float4*)out)[idx] = o;
}

// ---------------------------------------------------------------------------
// score fallback (R9, proven 60.2 us): 64x32 tile, 4x2/thread, grid 512.
// ---------------------------------------------------------------------------
__global__ __launch_bounds__(256, 2) void score_kernel_r9(
    const float* __restrict__ C,
    const float* __restrict__ w2,
    const float* __restrict__ b2,
    float* __restrict__ out)
{
  __shared__ float hs[2][64][36];
  __shared__ float ms[2][32][36];
  __shared__ float wred[4];

  const int tid = threadIdx.x;
  const int bi  = blockIdx.x & 15;
  const int bj  = blockIdx.x >> 4;
  const int i0  = bi * 64, j0 = bj * 32;
  const int ti  = tid >> 4, tj = tid & 15;

  const int sr  = tid >> 3;
  const int sk  = (tid & 7) << 2;

  float sw = 0.f;
  for (int t = tid; t < D_H; t += 256) sw += w2[t];
  #pragma unroll
  for (int off = 32; off > 0; off >>= 1) sw += __shfl_down(sw, off, 64);
  if ((tid & 63) == 0) wred[tid >> 6] = sw;

  const float* hrow0 = C + (size_t)(i0 + sr)      * 1024 + sk;
  const float* hrow1 = C + (size_t)(i0 + sr + 32) * 1024 + sk;
  const float* mrow  = C + (size_t)(j0 + sr) * 1024 + D_H + sk;

  float4 hv0 = *(const float4*)(hrow0);
  float4 hv1 = *(const float4*)(hrow1);
  float4 mv  = *(const float4*)(mrow);

  float acc[4][2] = {};
  int p = 0;

  float4 ehA[4], emA[2], ehB[4], emB[2];

  #define LOADG(EH, EM, KK)                                            \
  {                                                                    \
    _Pragma("unroll")                                                  \
    for (int a = 0; a < 4; ++a)                                        \
      (EH)[a] = *(const float4*)&hs[p][ti + 16*a][(KK)];               \
    _Pragma("unroll")                                                  \
    for (int c = 0; c < 2; ++c)                                        \
      (EM)[c] = *(const float4*)&ms[p][tj + 16*c][(KK)];               \
  }

  #define COMPG(EH, EM, KB)                                            \
  {                                                                    \
    const float wA = w2[(KB) + 0];                                     \
    const float wB = w2[(KB) + 1];                                     \
    const float wC = w2[(KB) + 2];                                     \
    const float wD = w2[(KB) + 3];                                     \
    _Pragma("unroll")                                                  \
    for (int a = 0; a < 4; ++a) {                                      \
      _Pragma("unroll")                                                \
      for (int c = 0; c < 2; ++c) {                                    \
        float uA = fmaf((EH)[a].x, (EM)[c].x, 1.f);                    \
        float uB = fmaf((EH)[a].y, (EM)[c].y, 1.f);                    \
        float uC = fmaf((EH)[a].z, (EM)[c].z, 1.f);                    \
        float uD = fmaf((EH)[a].w, (EM)[c].w, 1.f);                    \
        float dAB = uA * uB, dCD = uC * uD;                            \
        float nAB = fmaf(wB, uA, wA * uB);                             \
        float nCD = fmaf(wD, uC, wC * uD);                             \
        float den = dAB * dCD;                                         \
        float num = fmaf(nCD, dAB, nAB * dCD);                         \
        acc[a][c] = fmaf(num, __builtin_amdgcn_rcpf(den), acc[a][c]);  \
      }                                                                \
    }                                                                  \
  }

  for (int k0 = 0; k0 < D_H; k0 += 32) {
    *(float4*)&hs[p][sr][sk]      = hv0;
    *(float4*)&hs[p][sr + 32][sk] = hv1;
    *(float4*)&ms[p][sr][sk]      = mv;
    __syncthreads();

    if (k0 + 32 < D_H) {
      hv0 = *(const float4*)(hrow0 + k0 + 32);
      hv1 = *(const float4*)(hrow1 + k0 + 32);
      mv  = *(const float4*)(mrow  + k0 + 32);
    }

    LOADG(ehA, emA, 0)
    #pragma unroll
    for (int gp = 0; gp < 4; ++gp) {
      const int kk = 8 * gp;
      LOADG(ehB, emB, kk + 4)
      COMPG(ehA, emA, k0 + kk)
      if (gp < 3) { LOADG(ehA, emA, kk + 8) }
      COMPG(ehB, emB, k0 + kk + 4)
    }
    p ^= 1;
  }
  #undef LOADG
  #undef COMPG

  const float base = b2[0] + wred[0] + wred[1] + wred[2] + wred[3];
  #pragma unroll
  for (int a = 0; a < 4; ++a) {
    const int i = i0 + ti + 16*a;
    #pragma unroll
    for (int c = 0; c < 2; ++c) {
      const int j = j0 + tj + 16*c;
      out[(size_t)i * 1024 + j] = fmaf(-2.f, acc[a][c], base);
    }
  }
}

extern "C" void kernel_launch(void* const* d_in, const int* in_sizes, int n_in,
                              void* d_out, int out_size, void* d_ws, size_t ws_size,
                              hipStream_t stream) {
  const float* V  = (const float*)d_in[0];
  const float* Wh = (const float*)d_in[1];
  const float* bh = (const float*)d_in[2];
  const float* Wm = (const float*)d_in[3];
  const float* bm = (const float*)d_in[4];
  const float* w2 = (const float*)d_in[5];
  const float* b2 = (const float*)d_in[6];
  float* outp = (float*)d_out;

  char* ws = (char*)d_ws;
  float* C = (float*)ws;                                 // 4 MB: Eh|Em

  if (ws_size >= (size_t)(16u << 20)) {
    _Float16* Vh = (_Float16*)(ws + (4u << 20));         // 2 MB
    _Float16* Wf = (_Float16*)(ws + (6u << 20));         // 2 MB
    float*    P0 = (float*)(ws + (8u << 20));            // 4 MB
    float*    P1 = (float*)(ws + (12u << 20));           // 4 MB
    cvt_kernel<<<dim3(1024), dim3(256), 0, stream>>>(V, Wh, Wm, Vh, Wf);
    proj_mfma_kernel<<<dim3(1024), dim3(256), 0, stream>>>(Vh, Wf, bh, bm, C);
    score_split_kernel<<<dim3(512), dim3(256), 0, stream>>>(C, w2, b2, P0, P1);
    combine_kernel<<<dim3(1024), dim3(256), 0, stream>>>(P0, P1, outp);
  } else if (ws_size >= (size_t)(8u << 20)) {
    _Float16* Vh = (_Float16*)(ws + (4u << 20));         // 2 MB
    _Float16* Wf = (_Float16*)(ws + (6u << 20));         // 2 MB
    cvt_kernel<<<dim3(1024), dim3(256), 0, stream>>>(V, Wh, Wm, Vh, Wf);
    proj_mfma_kernel<<<dim3(1024), dim3(256), 0, stream>>>(Vh, Wf, bh, bm, C);
    score_kernel_r9<<<dim3(512), dim3(256), 0, stream>>>(C, w2, b2, outp);
  } else {
    proj_kernel<<<dim3(256), dim3(256), 0, stream>>>(V, Wh, bh, Wm, bm, C);
    score_kernel_r9<<<dim3(512), dim3(256), 0, stream>>>(C, w2, b2, outp);
  }
}